// Round 11
// baseline (1196.526 us; speedup 1.0000x reference)
//
#include <hip/hip_runtime.h>
#include <math.h>

#define NB 8
#define NT 1500
#define ND 1536
#define NP 1024
#define NE 192
#define NITER 6
#define NEGINF -1e30f

typedef __attribute__((ext_vector_type(8))) short bf16x8;
typedef __attribute__((ext_vector_type(4))) float f32x4;
typedef __attribute__((ext_vector_type(8))) unsigned short us16x8;

__device__ __forceinline__ unsigned short bf_rne(float x) {
    unsigned u = __float_as_uint(x);
    return (unsigned short)((u + 0x7FFFu + ((u >> 16) & 1u)) >> 16);
}
__device__ __forceinline__ float bf_f(unsigned short u) {
    return __uint_as_float(((unsigned)u) << 16);
}

// ---------------- helpers ----------------
__device__ __forceinline__ float block_reduce_sum(float v, float* red) {
    int tid = threadIdx.x;
    red[tid] = v; __syncthreads();
    for (int s = blockDim.x >> 1; s > 0; s >>= 1) {
        if (tid < s) red[tid] += red[tid + s];
        __syncthreads();
    }
    float r = red[0]; __syncthreads();
    return r;
}

// ---------------- pre-pass kernels ----------------
__global__ void k_colstats(const float* __restrict__ h, float* __restrict__ sum1,
                           float* __restrict__ sum2) {
    int d = blockIdx.x * 256 + threadIdx.x;
    int b = blockIdx.y;
    int t0 = blockIdx.z * 125, t1 = t0 + 125;
    const float* hp = h + (size_t)b * NT * ND + d;
    float s = 0.f, s2 = 0.f;
    for (int t = t0; t < t1; ++t) { float v = hp[(size_t)t * ND]; s += v; s2 += v * v; }
    atomicAdd(&sum1[b * ND + d], s);
    atomicAdd(&sum2[b * ND + d], s2);
}

__global__ void k_stats_fin(float* __restrict__ mu0, float* __restrict__ sig0) {
    int i = blockIdx.x * 256 + threadIdx.x;
    float mu = mu0[i] * (1.f / NT);
    float sec = sig0[i] * (1.f / NT);
    mu0[i] = mu;
    sig0[i] = sqrtf(fmaxf(sec - mu * mu, 1e-8f));
}

__global__ void k_w2r(const float* __restrict__ W2, const float* __restrict__ b2,
                      float* __restrict__ w2r, float* __restrict__ b2m) {
    __shared__ float red[256];
    int p = blockIdx.x;
    float s = 0.f;
    if (p < NP) {
        const float* row = W2 + (size_t)p * ND;
        for (int d = threadIdx.x; d < ND; d += 256) s += row[d];
        s = block_reduce_sum(s, red);
        if (threadIdx.x == 0) w2r[p] = s * (1.f / ND);
    } else {
        for (int d = threadIdx.x; d < ND; d += 256) s += b2[d];
        s = block_reduce_sum(s, red);
        if (threadIdx.x == 0) b2m[0] = s * (1.f / ND);
    }
}

// grid (4, 96), block 256
__global__ void k_biasb(const float* __restrict__ W1, const float* __restrict__ mu0,
                        const float* __restrict__ sig0, float* __restrict__ biasb) {
    int p = blockIdx.x * 256 + threadIdx.x;
    int d0 = blockIdx.y * 16, d1 = d0 + 16;
    float acc[NB];
#pragma unroll
    for (int b = 0; b < NB; ++b) acc[b] = 0.f;
    for (int d = d0; d < d1; ++d) {
        float wa = W1[(size_t)(ND + d) * NP + p];
        float wb = W1[(size_t)(2 * ND + d) * NP + p];
#pragma unroll
        for (int b = 0; b < NB; ++b)
            acc[b] += mu0[b * ND + d] * wa + sig0[b * ND + d] * wb;
    }
#pragma unroll
    for (int b = 0; b < NB; ++b) atomicAdd(&biasb[b * NP + p], acc[b]);
}

__global__ void k_init(float* __restrict__ C, const float* __restrict__ C0,
                       float* __restrict__ stopf) {
    int d = blockIdx.x * 256 + threadIdx.x;
    int b = blockIdx.y;
    C[b * ND + d] = C0[d];
    if (blockIdx.x == 0 && threadIdx.x == 0) stopf[b] = 0.f;
}

// ---------------- weight split (once): W [K][N] f32 -> tiled swizzled bf16 hi/lo ----------------
__global__ void k_split_w(const float* __restrict__ W, int ldw, int kcnt,
                          unsigned short* __restrict__ th, unsigned short* __restrict__ tl) {
    __shared__ float t[128][33];
    int nt = blockIdx.x, kc = blockIdx.y, tid = threadIdx.x;
    int col = tid & 127, kh = tid >> 7;
    const float* wp = W + (size_t)(kc * 32 + kh) * ldw + nt * 128 + col;
#pragma unroll
    for (int i = 0; i < 16; ++i)
        t[col][kh + 2 * i] = wp[(size_t)(2 * i) * ldw];
    __syncthreads();
    int r = tid >> 1;
    int swz = (r >> 1) & 3;
    size_t tb = ((size_t)nt * kcnt + kc) * 4096;
#pragma unroll
    for (int j = 0; j < 2; ++j) {
        int so = (tid & 1) * 2 + j;
        int s = so ^ swz;
        us16x8 hv, lv;
#pragma unroll
        for (int q = 0; q < 8; ++q) {
            float x = t[r][s * 8 + q];
            unsigned short hh = bf_rne(x);
            hv[q] = hh;
            lv[q] = bf_rne(x - bf_f(hh));
        }
        *(us16x8*)&th[tb + r * 32 + so * 8] = hv;
        *(us16x8*)&tl[tb + r * 32 + so * 8] = lv;
    }
}

// ---------------- h split (once): h f32 -> tiled swizzled bf16 hi + energy row sums ----------------
// grid (12, 48, NB), block 256
__global__ void k_split_h(const float* __restrict__ h, unsigned short* __restrict__ th,
                          float* __restrict__ energy) {
    int tr = blockIdx.x, kc = blockIdx.y, b = blockIdx.z;
    int tid = threadIdx.x;
    int r = tid >> 1, quad = tid & 1;
    int row = tr * 128 + r;
    bool ok = row < NT;
    size_t tb = ((size_t)(b * 12 + tr) * 48 + kc) * 4096;
    const float* hp = h + ((size_t)b * NT + (ok ? row : 0)) * ND + kc * 32 + quad * 16;
    int swz = (r >> 1) & 3;
    float es = 0.f;
#pragma unroll
    for (int half = 0; half < 2; ++half) {
        us16x8 hv;
#pragma unroll
        for (int j = 0; j < 2; ++j) {
            float x0 = 0.f, x1 = 0.f, x2 = 0.f, x3 = 0.f;
            if (ok) {
                float4 v = *(const float4*)(hp + half * 8 + j * 4);
                x0 = v.x; x1 = v.y; x2 = v.z; x3 = v.w;
                es += x0 * x0 + x1 * x1 + x2 * x2 + x3 * x3;
            }
            hv[j * 4 + 0] = bf_rne(x0); hv[j * 4 + 1] = bf_rne(x1);
            hv[j * 4 + 2] = bf_rne(x2); hv[j * 4 + 3] = bf_rne(x3);
        }
        int off = r * 32 + (((quad * 2 + half) ^ swz) << 3);
        *(us16x8*)&th[tb + off] = hv;
    }
    es += __shfl_xor(es, 1);
    if (ok && quad == 0) atomicAdd(&energy[b * NT + row], es);
}

// ---------------- per-iter: att row-sums only (no tile write) ----------------
// grid (375, NB), block 256 (4 waves, 1 row each)
__global__ void k_att(const unsigned short* __restrict__ base16,
                      const float* __restrict__ cvec, const float* __restrict__ w2r,
                      float* __restrict__ att) {
    __shared__ float cv_sh[NP], wr_sh[NP];
    int blk = blockIdx.x, b = blockIdx.y;
    int tid = threadIdx.x, lane = tid & 63, wv = tid >> 6;
    for (int i = tid; i < NP / 4; i += 256) {
        ((float4*)cv_sh)[i] = ((const float4*)(cvec + (size_t)b * NP))[i];
        ((float4*)wr_sh)[i] = ((const float4*)w2r)[i];
    }
    __syncthreads();
    int row = blk * 4 + wv;  // 375*4 = 1500 = NT exactly
    const unsigned short* bp = base16 + ((size_t)b * NT + row) * NP + lane * 16;
    us16x8 v0 = *(const us16x8*)bp;
    us16x8 v1 = *(const us16x8*)(bp + 8);
    float s = 0.f;
#pragma unroll
    for (int j = 0; j < 8; ++j)
        s += fmaxf(bf_f(v0[j]) + cv_sh[lane * 16 + j], 0.f) * wr_sh[lane * 16 + j];
#pragma unroll
    for (int j = 0; j < 8; ++j)
        s += fmaxf(bf_f(v1[j]) + cv_sh[lane * 16 + 8 + j], 0.f) * wr_sh[lane * 16 + 8 + j];
#pragma unroll
    for (int d = 1; d < 64; d <<= 1) s += __shfl_xor(s, d);
    if (lane == 0) att[b * NT + row] = s;
}

// ---------------- RELU GEMM: fused relu(base16+cvec) A-staging, dbuf BK=32 ----------------
__global__ __launch_bounds__(256, 4) void k_gemm_relu(
    const unsigned short* __restrict__ base16, const float* __restrict__ cvec,
    const unsigned short* __restrict__ ht, const unsigned short* __restrict__ bt_h,
    const float* __restrict__ b2, const float* __restrict__ Aw, float* __restrict__ part) {
    constexpr int KC = NP / 32;  // 32
    __shared__ __align__(16) unsigned short As[2][4096];
    __shared__ __align__(16) unsigned short Bs[2][4096];
    __shared__ float cv_sh[NP];
    int flat = blockIdx.x + 12 * (blockIdx.y + 12 * blockIdx.z);
    int swzf = (flat & 7) * 144 + (flat >> 3);
    int tr = swzf % 12, nt = (swzf / 12) % 12, b = swzf / 144;
    int tid = threadIdx.x;
    int lane = tid & 63, w = tid >> 6;
    int wr = w >> 1, wc = w & 1;
    int l15 = lane & 15, kg = lane >> 4;
    int sw = (l15 >> 1) & 3;
    f32x4 acc[4][4];
#pragma unroll
    for (int m = 0; m < 4; ++m)
#pragma unroll
        for (int n = 0; n < 4; ++n) acc[m][n] = (f32x4){0.f, 0.f, 0.f, 0.f};
    int aoff[4], boff[4];
#pragma unroll
    for (int m = 0; m < 4; ++m) aoff[m] = (wr * 64 + m * 16 + l15) * 32 + ((kg ^ sw) << 3);
#pragma unroll
    for (int n = 0; n < 4; ++n) boff[n] = (wc * 64 + n * 16 + l15) * 32 + ((kg ^ sw) << 3);

    const unsigned short* gb = bt_h + ((size_t)nt * KC) * 4096 + lane * 8;

    // A source: base16 rows (clamped), on-the-fly relu(base+cvec) -> bf16 -> LDS
    int r2 = tid >> 1, quad = tid & 1;
    int arow = tr * 128 + r2;
    int rowc = arow < NT ? arow : (NT - 1);
    int aswz = (r2 >> 1) & 3;
    const unsigned short* ap = base16 + ((size_t)b * NT + rowc) * NP + quad * 16;

    // preload cvec to LDS
    for (int i = tid; i < NP / 4; i += 256)
        ((float4*)cv_sh)[i] = ((const float4*)(cvec + (size_t)b * NP))[i];
    __syncthreads();

    auto stageB = [&](int buf, int kc) {
#pragma unroll
        for (int c = 0; c < 2; ++c) {
            int seg = w * 2 + c;  // 0..7
            const unsigned short* src = gb + (size_t)kc * 4096 + seg * 512;
            unsigned short* dst = &Bs[buf][0] + seg * 512;
            __builtin_amdgcn_global_load_lds(src, dst, 16, 0, 0);
        }
    };
    auto loadA = [&](int kc, us16x8* raw) {
        raw[0] = *(const us16x8*)(ap + kc * 32);
        raw[1] = *(const us16x8*)(ap + kc * 32 + 8);
    };
    auto writeA = [&](int buf, const us16x8* raw, int kc) {
#pragma unroll
        for (int half = 0; half < 2; ++half) {
            us16x8 hv;
#pragma unroll
            for (int j = 0; j < 8; ++j) {
                float x = bf_f(raw[half][j]) + cv_sh[kc * 32 + quad * 16 + half * 8 + j];
                hv[j] = bf_rne(fmaxf(x, 0.f));
            }
            int so = quad * 2 + half;
            int off = r2 * 32 + ((so ^ aswz) << 3);
            *(us16x8*)&As[buf][off] = hv;
        }
    };

    {
        us16x8 raw0[2];
        stageB(0, 0);
        loadA(0, raw0);
        writeA(0, raw0, 0);
    }
    __syncthreads();
    int cur = 0;
    for (int kc = 0; kc < KC; ++kc) {
        bool np = kc + 1 < KC;
        us16x8 rawn[2];
        if (np) {
            stageB(cur ^ 1, kc + 1);
            loadA(kc + 1, rawn);
        }
        bf16x8 af[4], bfr[4];
#pragma unroll
        for (int m = 0; m < 4; ++m) af[m] = *(const bf16x8*)&As[cur][aoff[m]];
#pragma unroll
        for (int n = 0; n < 4; ++n) bfr[n] = *(const bf16x8*)&Bs[cur][boff[n]];
#pragma unroll
        for (int n = 0; n < 4; ++n)
#pragma unroll
            for (int m = 0; m < 4; ++m)
                acc[m][n] = __builtin_amdgcn_mfma_f32_16x16x32_bf16(af[m], bfr[n], acc[m][n], 0, 0, 0);
        if (np) writeA(cur ^ 1, rawn, kc + 1);
        __syncthreads();
        cur ^= 1;
    }

    int rowb = tr * 128 + wr * 64 + (kg << 2);
    int colb = nt * 128 + wc * 64 + l15;
    const unsigned short* htb = ht + (size_t)(b * 12 + tr) * 48 * 4096;
    float b2c[4];
#pragma unroll
    for (int n = 0; n < 4; ++n) b2c[n] = b2[colb + n * 16];
    float pm[4] = {0, 0, 0, 0}, ps2[4] = {0, 0, 0, 0}, pza[4] = {0, 0, 0, 0}, pah[4] = {0, 0, 0, 0};
#pragma unroll
    for (int m = 0; m < 4; ++m) {
#pragma unroll
        for (int q = 0; q < 4; ++q) {
            int row = rowb + m * 16 + q;
            int r_in = wr * 64 + (kg << 2) + m * 16 + q;
            bool ok = row < NT;
            float okf = ok ? 1.f : 0.f;
            float a = Aw[b * NT + (ok ? row : (NT - 1))] * okf;
            int rsw = (r_in >> 1) & 3;
#pragma unroll
            for (int n = 0; n < 4; ++n) {
                int col = colb + n * 16;
                float hv = bf_f(htb[(size_t)(col >> 5) * 4096 + r_in * 32 +
                                    ((((col & 31) >> 3) ^ rsw) << 3) + (col & 7)]) * okf;
                float o2 = acc[m][n][q] + b2c[n];
                pm[n] = fmaf(o2, hv, pm[n]);
                ps2[n] = fmaf(o2 * hv, hv, ps2[n]);
                pza[n] = fmaf(a, o2, pza[n]);
                pah[n] = fmaf(a, hv, pah[n]);
            }
        }
    }
#pragma unroll
    for (int n = 0; n < 4; ++n) {
        pm[n] += __shfl_xor(pm[n], 16); pm[n] += __shfl_xor(pm[n], 32);
        ps2[n] += __shfl_xor(ps2[n], 16); ps2[n] += __shfl_xor(ps2[n], 32);
        pza[n] += __shfl_xor(pza[n], 16); pza[n] += __shfl_xor(pza[n], 32);
        pah[n] += __shfl_xor(pah[n], 16); pah[n] += __shfl_xor(pah[n], 32);
        if (kg == 0) {
            int col = colb + n * 16;
            size_t pb = (((size_t)(tr * 2 + wr) * NB + b) * 4) * ND;
            part[pb + 0 * (size_t)ND + col] = pm[n];
            part[pb + 1 * (size_t)ND + col] = ps2[n];
            part[pb + 2 * (size_t)ND + col] = pza[n];
            part[pb + 3 * (size_t)ND + col] = pah[n];
        }
    }
}

// sum 24 partial slices into red4; grid 48, block 256
__global__ void k_redsum(const float* __restrict__ part, float* __restrict__ red4) {
    int idx = blockIdx.x * 256 + threadIdx.x;  // b*ND + d
    int b = idx / ND, d = idx % ND;
    float s0 = 0.f, s1 = 0.f, s2 = 0.f, s3 = 0.f;
    for (int s = 0; s < 24; ++s) {
        const float* p = part + (((size_t)s * NB + b) * 4) * ND + d;
        s0 += p[0];
        s1 += p[(size_t)ND];
        s2 += p[2 * (size_t)ND];
        s3 += p[3 * (size_t)ND];
    }
    red4[idx] = s0;                          // mu_p
    red4[(size_t)NB * ND + idx] = s1;        // second
    red4[3 * (size_t)NB * ND + idx] = s2;    // zA
    red4[2 * (size_t)NB * ND + idx] = s3;    // A.h
}

// ---------------- base GEMM: 2-term Ah*(Bh+Bl), BK=64 single-buffered ----------------
__global__ __launch_bounds__(256, 3) void k_gemm_base(
    const unsigned short* __restrict__ ht, const unsigned short* __restrict__ bt_h,
    const unsigned short* __restrict__ bt_l, const float* __restrict__ biasb,
    unsigned short* __restrict__ Out16) {
    constexpr int KC2 = ND / 64;  // 24
    __shared__ __align__(16) unsigned short As[8192];
    __shared__ __align__(16) unsigned short Bh_s[8192];
    __shared__ __align__(16) unsigned short Bl_s[8192];
    int flat = blockIdx.x + 12 * (blockIdx.y + 8 * blockIdx.z);
    int swzf = (flat & 7) * 96 + (flat >> 3);
    int tr = swzf % 12, nt = (swzf / 12) % 8, b = swzf / 96;
    int tid = threadIdx.x;
    int lane = tid & 63, w = tid >> 6;
    int wr = w >> 1, wc = w & 1;
    int l15 = lane & 15, kg = lane >> 4;
    int sw = (l15 >> 1) & 3;
    f32x4 acc[4][4];
#pragma unroll
    for (int m = 0; m < 4; ++m)
#pragma unroll
        for (int n = 0; n < 4; ++n) acc[m][n] = (f32x4){0.f, 0.f, 0.f, 0.f};
    int aoff[4], boff[4];
#pragma unroll
    for (int m = 0; m < 4; ++m) aoff[m] = (wr * 64 + m * 16 + l15) * 32 + ((kg ^ sw) << 3);
#pragma unroll
    for (int n = 0; n < 4; ++n) boff[n] = (wc * 64 + n * 16 + l15) * 32 + ((kg ^ sw) << 3);

    const unsigned short* ga = ht + ((size_t)(b * 12 + tr) * 48) * 4096 + lane * 8;
    const unsigned short* gbh = bt_h + ((size_t)nt * 48) * 4096 + lane * 8;
    const unsigned short* gbl = bt_l + ((size_t)nt * 48) * 4096 + lane * 8;

    for (int kc2 = 0; kc2 < KC2; ++kc2) {
#pragma unroll
        for (int c = 0; c < 12; ++c) {
            int seg = w * 12 + c;        // 0..47
            int part = seg & 15, mat = seg >> 4;
            const unsigned short* src =
                (mat == 0 ? ga : mat == 1 ? gbh : gbl) + (size_t)kc2 * 8192 + part * 512;
            unsigned short* dst =
                (mat == 0 ? &As[0] : mat == 1 ? &Bh_s[0] : &Bl_s[0]) + part * 512;
            __builtin_amdgcn_global_load_lds(src, dst, 16, 0, 0);
        }
        __syncthreads();
#pragma unroll
        for (int half = 0; half < 2; ++half) {
            int ho = half * 4096;
            bf16x8 af[4];
#pragma unroll
            for (int m = 0; m < 4; ++m) af[m] = *(const bf16x8*)&As[ho + aoff[m]];
#pragma unroll
            for (int n = 0; n < 4; ++n) {
                bf16x8 bh = *(const bf16x8*)&Bh_s[ho + boff[n]];
                bf16x8 bl = *(const bf16x8*)&Bl_s[ho + boff[n]];
#pragma unroll
                for (int m = 0; m < 4; ++m) {
                    acc[m][n] = __builtin_amdgcn_mfma_f32_16x16x32_bf16(af[m], bh, acc[m][n], 0, 0, 0);
                    acc[m][n] = __builtin_amdgcn_mfma_f32_16x16x32_bf16(af[m], bl, acc[m][n], 0, 0, 0);
                }
            }
        }
        __syncthreads();
    }

    int rowb = tr * 128 + wr * 64 + (kg << 2);
    int colb = nt * 128 + wc * 64 + l15;
#pragma unroll
    for (int m = 0; m < 4; ++m)
#pragma unroll
        for (int q = 0; q < 4; ++q) {
            int row = rowb + m * 16 + q;
            if (row < NT) {
                unsigned short* orow = Out16 + ((size_t)b * NT + row) * NP;
#pragma unroll
                for (int n = 0; n < 4; ++n)
                    orow[colb + n * 16] =
                        bf_rne(acc[m][n][q] + biasb[b * NP + colb + n * 16]);
            }
        }
}

// ---------------- per-iteration small kernels ----------------
// grid (4, 32), block 256
__global__ void k_cvec(const float* __restrict__ C, const float* __restrict__ Wc,
                       float* __restrict__ cvec) {
    int p = blockIdx.x * 256 + threadIdx.x;
    int d0 = blockIdx.y * 48, d1 = d0 + 48;
    float acc[NB];
#pragma unroll
    for (int b = 0; b < NB; ++b) acc[b] = 0.f;
    for (int d = d0; d < d1; ++d) {
        float wc = Wc[(size_t)d * NP + p];
#pragma unroll
        for (int b = 0; b < NB; ++b) acc[b] += C[b * ND + d] * wc;
    }
#pragma unroll
    for (int b = 0; b < NB; ++b) atomicAdd(&cvec[b * NP + p], acc[b]);
}

__global__ void k_softmax(const float* __restrict__ att, const float* __restrict__ energy,
                          const float* __restrict__ b2m, float* __restrict__ A) {
    __shared__ float red[256];
    int b = blockIdx.x, tid = threadIdx.x;
    float bm = b2m[0];
    const float* x = att + (size_t)b * NT;
    const float* en = energy + (size_t)b * NT;
    float* a = A + (size_t)b * NT;
    float mx = -3.4e38f;
    for (int t = tid; t < NT; t += 256) {
        float v = (en[t] * (1.f / ND) > 1e-4f) ? x[t] + bm : NEGINF;
        mx = fmaxf(mx, v);
    }
    red[tid] = mx; __syncthreads();
    for (int s = 128; s > 0; s >>= 1) {
        if (tid < s) red[tid] = fmaxf(red[tid], red[tid + s]);
        __syncthreads();
    }
    mx = red[0]; __syncthreads();
    float sm = 0.f;
    for (int t = tid; t < NT; t += 256) {
        float v = (en[t] * (1.f / ND) > 1e-4f) ? x[t] + bm : NEGINF;
        float e = expf(v - mx); a[t] = e; sm += e;
    }
    float s1 = block_reduce_sum(sm, red);
    float inv1 = 1.f / s1;
    float sm2 = 0.f;
    for (int t = tid; t < NT; t += 256) { float v = a[t] * inv1; a[t] = v; sm2 += v; }
    float s2 = block_reduce_sum(sm2, red);
    float inv2 = 1.f / (s2 + 1e-8f);
    for (int t = tid; t < NT; t += 256) a[t] *= inv2;
}

// parallel emb accumulation: grid 32, block 192
__global__ void k_embacc(const float* __restrict__ red4, const float* __restrict__ w0,
                         float* __restrict__ embt) {
    __shared__ float mus[NB][48], sgs[NB][48];
    int e = threadIdx.x;
    int d0 = blockIdx.x * 48;
    const float* mup = red4;
    const float* s2p = red4 + (size_t)NB * ND;
    for (int idx = e; idx < NB * 48; idx += 192) {
        int b = idx / 48, dd = idx % 48;
        float mu = mup[b * ND + d0 + dd];
        mus[b][dd] = mu;
        sgs[b][dd] = sqrtf(fmaxf(s2p[b * ND + d0 + dd] - mu * mu, 1e-8f));
    }
    __syncthreads();
    float acc[NB];
#pragma unroll
    for (int b = 0; b < NB; ++b) acc[b] = 0.f;
    for (int dd = 0; dd < 48; ++dd) {
        float wa = w0[(size_t)(d0 + dd) * NE + e];
        float wb = w0[(size_t)(ND + d0 + dd) * NE + e];
#pragma unroll
        for (int b = 0; b < NB; ++b)
            acc[b] += mus[b][dd] * wa + sgs[b][dd] * wb;
    }
#pragma unroll
    for (int b = 0; b < NB; ++b) atomicAdd(&embt[b * NE + e], acc[b]);
}

// C-update + stop prob + masked emb-norm write; grid NB, block 256
__global__ void k_tail2(const float* __restrict__ red4, const float* __restrict__ embt,
                        const float* __restrict__ b0, const float* __restrict__ Wstop,
                        const float* __restrict__ bstop, const float* __restrict__ thr,
                        float* __restrict__ Cb, float* __restrict__ stopf,
                        float* __restrict__ Eout, float* __restrict__ Pout, int iter) {
    __shared__ float red[256];
    __shared__ float liveflag;
    int b = blockIdx.x, tid = threadIdx.x;
    const float* Ahb = red4 + (size_t)2 * NB * ND + b * ND;
    const float* zAb = red4 + (size_t)3 * NB * ND + b * ND;
    float active = (stopf[b] > 0.5f) ? 0.f : 1.f;
    float dsum = 0.f;
    for (int d = tid; d < ND; d += 256) {
        float Cn = Cb[b * ND + d] + active * (Ahb[d] * (1.f / NT));
        Cb[b * ND + d] = Cn;
        dsum += zAb[d] * Wstop[d] + Cn * Wstop[ND + d];
    }
    float s = block_reduce_sum(dsum, red);
    if (tid == 0) {
        float logit = s + bstop[0];
        float p = 1.f / (1.f + expf(-logit));
        Pout[b * NITER + iter] = p;
        bool newly = p < thr[0];
        if (newly) stopf[b] = 1.f;
        liveflag = (active > 0.5f && !newly) ? 1.f : 0.f;
    }
    __syncthreads();
    float live = liveflag;
    float emb = (tid < NE) ? (embt[b * NE + tid] + b0[tid]) : 0.f;
    float nrm = block_reduce_sum(emb * emb, red);
    float sc = live / fmaxf(sqrtf(nrm), 1e-12f);
    if (tid < NE) Eout[((size_t)b * NITER + iter) * NE + tid] = emb * sc;
}

// ---------------- launch ----------------
extern "C" void kernel_launch(void* const* d_in, const int* in_sizes, int n_in,
                              void* d_out, int out_size, void* d_ws, size_t ws_size,
                              hipStream_t stream) {
    const float* h = (const float*)d_in[0];
    const float* W1 = (const float*)d_in[1];
    const float* Wc = (const float*)d_in[2];
    const float* W2 = (const float*)d_in[3];
    const float* b2 = (const float*)d_in[4];
    const float* w0 = (const float*)d_in[5];
    const float* b0 = (const float*)d_in[6];
    const float* Wstop = (const float*)d_in[7];
    const float* bstop = (const float*)d_in[8];
    const float* thr = (const float*)d_in[9];
    const float* C0 = (const float*)d_in[10];

    float* Eout = (float*)d_out;
    float* Pout = Eout + (size_t)NB * NITER * NE;

    char* wsb = (char*)d_ws;
    size_t off = 0;
    auto alloc = [&](size_t bytes) -> void* {
        void* p = wsb + off; off += (bytes + 15) & ~(size_t)15; return p;
    };

    unsigned short* base16 = (unsigned short*)alloc((size_t)NB * NT * NP * 2);
    unsigned short* ht_h = (unsigned short*)alloc((size_t)NB * 12 * 48 * 4096 * 2);
    unsigned short* w1t_h = (unsigned short*)alloc((size_t)8 * 48 * 4096 * 2);
    unsigned short* w1t_l = (unsigned short*)alloc((size_t)8 * 48 * 4096 * 2);
    unsigned short* w2t_h = (unsigned short*)alloc((size_t)12 * 32 * 4096 * 2);
    unsigned short* w2t_l = (unsigned short*)alloc((size_t)12 * 32 * 4096 * 2);
    // pre-pass zero region: mu0 | sig0 | energy | biasb (one memset)
    size_t pz = (size_t)2 * NB * ND + NB * NT + NB * NP;
    float* mu0 = (float*)alloc(pz * 4);
    float* sig0 = mu0 + NB * ND;
    float* energy = sig0 + NB * ND;
    float* biasb = energy + NB * NT;
    float* w2r = (float*)alloc(NP * 4);
    float* b2m = (float*)alloc(16);
    // per-iter zero region: cvec | embt
    size_t zelems = (size_t)NB * NP + NB * NE;
    float* cvec = (float*)alloc(zelems * 4);
    float* embt = cvec + NB * NP;
    float* att = (float*)alloc((size_t)NB * NT * 4);
    float* red4 = (float*)alloc((size_t)4 * NB * ND * 4);
    float* part = (float*)alloc((size_t)24 * NB * 4 * ND * 4);
    float* Abuf = (float*)alloc(NB * NT * 4);
    float* Cb = (float*)alloc(NB * ND * 4);
    float* stopf = (float*)alloc(32);
    size_t zero_bytes = zelems * 4;

    // ---- pre-pass ----
    hipMemsetAsync(mu0, 0, pz * 4, stream);
    k_colstats<<<dim3(ND / 256, NB, 12), 256, 0, stream>>>(h, mu0, sig0);
    k_stats_fin<<<dim3(NB * ND / 256), 256, 0, stream>>>(mu0, sig0);
    k_w2r<<<dim3(NP + 1), 256, 0, stream>>>(W2, b2, w2r, b2m);
    k_biasb<<<dim3(4, 96), 256, 0, stream>>>(W1, mu0, sig0, biasb);
    k_split_w<<<dim3(8, 48), 256, 0, stream>>>(W1, NP, 48, w1t_h, w1t_l);
    k_split_w<<<dim3(12, 32), 256, 0, stream>>>(W2, ND, 32, w2t_h, w2t_l);
    k_split_h<<<dim3(12, 48, NB), 256, 0, stream>>>(h, ht_h, energy);
    k_gemm_base<<<dim3(12, 8, NB), 256, 0, stream>>>(ht_h, w1t_h, w1t_l, biasb, base16);
    k_init<<<dim3(ND / 256, NB), 256, 0, stream>>>(Cb, C0, stopf);

    // ---- iterations ----
    for (int i = 0; i < NITER; ++i) {
        hipMemsetAsync(cvec, 0, zero_bytes, stream);
        k_cvec<<<dim3(4, 32), 256, 0, stream>>>(Cb, Wc, cvec);
        k_att<<<dim3(375, NB), 256, 0, stream>>>(base16, cvec, w2r, att);
        k_softmax<<<dim3(NB), 256, 0, stream>>>(att, energy, b2m, Abuf);
        k_gemm_relu<<<dim3(12, 12, NB), 256, 0, stream>>>(
            base16, cvec, ht_h, w2t_h, b2, Abuf, part);
        k_redsum<<<dim3(48), 256, 0, stream>>>(part, red4);
        k_embacc<<<dim3(32), 192, 0, stream>>>(red4, w0, embt);
        k_tail2<<<dim3(NB), 256, 0, stream>>>(red4, embt, b0, Wstop, bstop, thr,
                                              Cb, stopf, Eout, Pout, i);
    }
}

// Round 12
// 1045.480 us; speedup vs baseline: 1.1445x; 1.1445x over previous
//
#include <hip/hip_runtime.h>
#include <math.h>

#define NB 8
#define NT 1500
#define ND 1536
#define NP 1024
#define NE 192
#define NITER 6
#define NEGINF -1e30f

typedef __attribute__((ext_vector_type(8))) short bf16x8;
typedef __attribute__((ext_vector_type(4))) float f32x4;
typedef __attribute__((ext_vector_type(8))) unsigned short us16x8;

__device__ __forceinline__ unsigned short bf_rne(float x) {
    unsigned u = __float_as_uint(x);
    return (unsigned short)((u + 0x7FFFu + ((u >> 16) & 1u)) >> 16);
}
__device__ __forceinline__ float bf_f(unsigned short u) {
    return __uint_as_float(((unsigned)u) << 16);
}

// ---------------- helpers ----------------
__device__ __forceinline__ float block_reduce_sum(float v, float* red) {
    int tid = threadIdx.x;
    red[tid] = v; __syncthreads();
    for (int s = blockDim.x >> 1; s > 0; s >>= 1) {
        if (tid < s) red[tid] += red[tid + s];
        __syncthreads();
    }
    float r = red[0]; __syncthreads();
    return r;
}

// ---------------- pre-pass kernels ----------------
__global__ void k_colstats(const float* __restrict__ h, float* __restrict__ sum1,
                           float* __restrict__ sum2) {
    int d = blockIdx.x * 256 + threadIdx.x;
    int b = blockIdx.y;
    int t0 = blockIdx.z * 125, t1 = t0 + 125;
    const float* hp = h + (size_t)b * NT * ND + d;
    float s = 0.f, s2 = 0.f;
    for (int t = t0; t < t1; ++t) { float v = hp[(size_t)t * ND]; s += v; s2 += v * v; }
    atomicAdd(&sum1[b * ND + d], s);
    atomicAdd(&sum2[b * ND + d], s2);
}

__global__ void k_stats_fin(float* __restrict__ mu0, float* __restrict__ sig0) {
    int i = blockIdx.x * 256 + threadIdx.x;
    float mu = mu0[i] * (1.f / NT);
    float sec = sig0[i] * (1.f / NT);
    mu0[i] = mu;
    sig0[i] = sqrtf(fmaxf(sec - mu * mu, 1e-8f));
}

__global__ void k_w2r(const float* __restrict__ W2, const float* __restrict__ b2,
                      float* __restrict__ w2r, float* __restrict__ b2m) {
    __shared__ float red[256];
    int p = blockIdx.x;
    float s = 0.f;
    if (p < NP) {
        const float* row = W2 + (size_t)p * ND;
        for (int d = threadIdx.x; d < ND; d += 256) s += row[d];
        s = block_reduce_sum(s, red);
        if (threadIdx.x == 0) w2r[p] = s * (1.f / ND);
    } else {
        for (int d = threadIdx.x; d < ND; d += 256) s += b2[d];
        s = block_reduce_sum(s, red);
        if (threadIdx.x == 0) b2m[0] = s * (1.f / ND);
    }
}

// grid (4, 96), block 256
__global__ void k_biasb(const float* __restrict__ W1, const float* __restrict__ mu0,
                        const float* __restrict__ sig0, float* __restrict__ biasb) {
    int p = blockIdx.x * 256 + threadIdx.x;
    int d0 = blockIdx.y * 16, d1 = d0 + 16;
    float acc[NB];
#pragma unroll
    for (int b = 0; b < NB; ++b) acc[b] = 0.f;
    for (int d = d0; d < d1; ++d) {
        float wa = W1[(size_t)(ND + d) * NP + p];
        float wb = W1[(size_t)(2 * ND + d) * NP + p];
#pragma unroll
        for (int b = 0; b < NB; ++b)
            acc[b] += mu0[b * ND + d] * wa + sig0[b * ND + d] * wb;
    }
#pragma unroll
    for (int b = 0; b < NB; ++b) atomicAdd(&biasb[b * NP + p], acc[b]);
}

__global__ void k_init(float* __restrict__ C, const float* __restrict__ C0,
                       float* __restrict__ stopf) {
    int d = blockIdx.x * 256 + threadIdx.x;
    int b = blockIdx.y;
    C[b * ND + d] = C0[d];
    if (blockIdx.x == 0 && threadIdx.x == 0) stopf[b] = 0.f;
}

// ---------------- weight split (once): W [K][N] f32 -> tiled swizzled bf16 hi/lo ----------------
__global__ void k_split_w(const float* __restrict__ W, int ldw, int kcnt,
                          unsigned short* __restrict__ th, unsigned short* __restrict__ tl) {
    __shared__ float t[128][33];
    int nt = blockIdx.x, kc = blockIdx.y, tid = threadIdx.x;
    int col = tid & 127, kh = tid >> 7;
    const float* wp = W + (size_t)(kc * 32 + kh) * ldw + nt * 128 + col;
#pragma unroll
    for (int i = 0; i < 16; ++i)
        t[col][kh + 2 * i] = wp[(size_t)(2 * i) * ldw];
    __syncthreads();
    int r = tid >> 1;
    int swz = (r >> 1) & 3;
    size_t tb = ((size_t)nt * kcnt + kc) * 4096;
#pragma unroll
    for (int j = 0; j < 2; ++j) {
        int so = (tid & 1) * 2 + j;
        int s = so ^ swz;
        us16x8 hv, lv;
#pragma unroll
        for (int q = 0; q < 8; ++q) {
            float x = t[r][s * 8 + q];
            unsigned short hh = bf_rne(x);
            hv[q] = hh;
            lv[q] = bf_rne(x - bf_f(hh));
        }
        *(us16x8*)&th[tb + r * 32 + so * 8] = hv;
        *(us16x8*)&tl[tb + r * 32 + so * 8] = lv;
    }
}

// ---------------- h split (once): h f32 -> tiled swizzled bf16 hi + energy row sums ----------------
// grid (12, 48, NB), block 256
__global__ void k_split_h(const float* __restrict__ h, unsigned short* __restrict__ th,
                          float* __restrict__ energy) {
    int tr = blockIdx.x, kc = blockIdx.y, b = blockIdx.z;
    int tid = threadIdx.x;
    int r = tid >> 1, quad = tid & 1;
    int row = tr * 128 + r;
    bool ok = row < NT;
    size_t tb = ((size_t)(b * 12 + tr) * 48 + kc) * 4096;
    const float* hp = h + ((size_t)b * NT + (ok ? row : 0)) * ND + kc * 32 + quad * 16;
    int swz = (r >> 1) & 3;
    float es = 0.f;
#pragma unroll
    for (int half = 0; half < 2; ++half) {
        us16x8 hv;
#pragma unroll
        for (int j = 0; j < 2; ++j) {
            float x0 = 0.f, x1 = 0.f, x2 = 0.f, x3 = 0.f;
            if (ok) {
                float4 v = *(const float4*)(hp + half * 8 + j * 4);
                x0 = v.x; x1 = v.y; x2 = v.z; x3 = v.w;
                es += x0 * x0 + x1 * x1 + x2 * x2 + x3 * x3;
            }
            hv[j * 4 + 0] = bf_rne(x0); hv[j * 4 + 1] = bf_rne(x1);
            hv[j * 4 + 2] = bf_rne(x2); hv[j * 4 + 3] = bf_rne(x3);
        }
        int off = r * 32 + (((quad * 2 + half) ^ swz) << 3);
        *(us16x8*)&th[tb + off] = hv;
    }
    es += __shfl_xor(es, 1);
    if (ok && quad == 0) atomicAdd(&energy[b * NT + row], es);
}

// ---------------- per-iter fused: relu(bf16 base + cvec) -> hi tile, + att partial sums ----------------
// grid (12, 32, NB), block 256
__global__ void k_relu_att(const unsigned short* __restrict__ base16,
                           const float* __restrict__ cvec, const float* __restrict__ w2r,
                           unsigned short* __restrict__ th, float* __restrict__ att) {
    int tr = blockIdx.x, kc = blockIdx.y, b = blockIdx.z;
    int tid = threadIdx.x;
    int r = tid >> 1, quad = tid & 1;
    int row = tr * 128 + r;
    bool ok = row < NT;
    size_t tb = ((size_t)(b * 12 + tr) * 32 + kc) * 4096;
    const unsigned short* bp = base16 + ((size_t)b * NT + (ok ? row : 0)) * NP + kc * 32 + quad * 16;
    const float* cv = cvec + b * NP + kc * 32 + quad * 16;
    const float* wr = w2r + kc * 32 + quad * 16;
    int swz = (r >> 1) & 3;
    float asum = 0.f;
#pragma unroll
    for (int half = 0; half < 2; ++half) {
        us16x8 bv = (us16x8){0, 0, 0, 0, 0, 0, 0, 0};
        if (ok) bv = *(const us16x8*)(bp + half * 8);
        us16x8 hv;
#pragma unroll
        for (int j = 0; j < 2; ++j) {
            float4 c4 = *(const float4*)(cv + half * 8 + j * 4);
            float4 w4 = *(const float4*)(wr + half * 8 + j * 4);
            float x0 = fmaxf(bf_f(bv[j * 4 + 0]) + c4.x, 0.f);
            float x1 = fmaxf(bf_f(bv[j * 4 + 1]) + c4.y, 0.f);
            float x2 = fmaxf(bf_f(bv[j * 4 + 2]) + c4.z, 0.f);
            float x3 = fmaxf(bf_f(bv[j * 4 + 3]) + c4.w, 0.f);
            if (ok) asum += x0 * w4.x + x1 * w4.y + x2 * w4.z + x3 * w4.w;
            hv[j * 4 + 0] = bf_rne(x0); hv[j * 4 + 1] = bf_rne(x1);
            hv[j * 4 + 2] = bf_rne(x2); hv[j * 4 + 3] = bf_rne(x3);
        }
        int off = r * 32 + (((quad * 2 + half) ^ swz) << 3);
        *(us16x8*)&th[tb + off] = hv;
    }
    asum += __shfl_xor(asum, 1);
    if (ok && quad == 0) atomicAdd(&att[b * NT + row], asum);
}

// ---------------- RELU GEMM: 1-term bf16, dbuf BK=32 + __syncthreads (r8 structure) ----------------
__global__ __launch_bounds__(256, 4) void k_gemm_relu(
    const unsigned short* __restrict__ ht, const unsigned short* __restrict__ at_h,
    const unsigned short* __restrict__ bt_h, const float* __restrict__ b2,
    const float* __restrict__ Aw, float* __restrict__ mup, float* __restrict__ s2p,
    float* __restrict__ zab, float* __restrict__ ahb) {
    constexpr int KC = NP / 32;  // 32
    __shared__ __align__(16) unsigned short As[2][4096];
    __shared__ __align__(16) unsigned short Bs[2][4096];
    int flat = blockIdx.x + 12 * (blockIdx.y + 12 * blockIdx.z);
    int swzf = (flat & 7) * 144 + (flat >> 3);
    int tr = swzf % 12, nt = (swzf / 12) % 12, b = swzf / 144;
    int tid = threadIdx.x;
    int lane = tid & 63, w = tid >> 6;
    int wr = w >> 1, wc = w & 1;
    int l15 = lane & 15, kg = lane >> 4;
    int sw = (l15 >> 1) & 3;
    f32x4 acc[4][4];
#pragma unroll
    for (int m = 0; m < 4; ++m)
#pragma unroll
        for (int n = 0; n < 4; ++n) acc[m][n] = (f32x4){0.f, 0.f, 0.f, 0.f};
    int aoff[4], boff[4];
#pragma unroll
    for (int m = 0; m < 4; ++m) aoff[m] = (wr * 64 + m * 16 + l15) * 32 + ((kg ^ sw) << 3);
#pragma unroll
    for (int n = 0; n < 4; ++n) boff[n] = (wc * 64 + n * 16 + l15) * 32 + ((kg ^ sw) << 3);

    const unsigned short* ga = at_h + ((size_t)(b * 12 + tr) * KC) * 4096 + lane * 8;
    const unsigned short* gb = bt_h + ((size_t)nt * KC) * 4096 + lane * 8;

    auto stage = [&](int buf, int kc) {
#pragma unroll
        for (int c = 0; c < 4; ++c) {
            int seg = w * 4 + c;
            int part_ = seg & 7;
            const unsigned short* src = ((seg >> 3) == 0 ? ga : gb) + (size_t)kc * 4096 + part_ * 512;
            unsigned short* dst = ((seg >> 3) == 0 ? &As[buf][0] : &Bs[buf][0]) + part_ * 512;
            __builtin_amdgcn_global_load_lds(src, dst, 16, 0, 0);
        }
    };

    stage(0, 0);
    __syncthreads();
    int cur = 0;
    for (int kc = 0; kc < KC; ++kc) {
        if (kc + 1 < KC) stage(cur ^ 1, kc + 1);
        bf16x8 af[4], bfr[4];
#pragma unroll
        for (int m = 0; m < 4; ++m) af[m] = *(const bf16x8*)&As[cur][aoff[m]];
#pragma unroll
        for (int n = 0; n < 4; ++n) bfr[n] = *(const bf16x8*)&Bs[cur][boff[n]];
#pragma unroll
        for (int n = 0; n < 4; ++n)
#pragma unroll
            for (int m = 0; m < 4; ++m)
                acc[m][n] = __builtin_amdgcn_mfma_f32_16x16x32_bf16(af[m], bfr[n], acc[m][n], 0, 0, 0);
        __syncthreads();
        cur ^= 1;
    }

    int rowb = tr * 128 + wr * 64 + (kg << 2);
    int colb = nt * 128 + wc * 64 + l15;
    const unsigned short* htb = ht + (size_t)(b * 12 + tr) * 48 * 4096;
    float b2c[4];
#pragma unroll
    for (int n = 0; n < 4; ++n) b2c[n] = b2[colb + n * 16];
    float pm[4] = {0, 0, 0, 0}, ps2[4] = {0, 0, 0, 0}, pza[4] = {0, 0, 0, 0}, pah[4] = {0, 0, 0, 0};
#pragma unroll
    for (int m = 0; m < 4; ++m) {
#pragma unroll
        for (int q = 0; q < 4; ++q) {
            int row = rowb + m * 16 + q;
            int r_in = wr * 64 + (kg << 2) + m * 16 + q;
            bool ok = row < NT;
            float okf = ok ? 1.f : 0.f;
            float a = Aw[b * NT + (ok ? row : (NT - 1))] * okf;
            int rsw = (r_in >> 1) & 3;
#pragma unroll
            for (int n = 0; n < 4; ++n) {
                int col = colb + n * 16;
                float hv = bf_f(htb[(size_t)(col >> 5) * 4096 + r_in * 32 +
                                    ((((col & 31) >> 3) ^ rsw) << 3) + (col & 7)]) * okf;
                float o2 = acc[m][n][q] + b2c[n];
                pm[n] = fmaf(o2, hv, pm[n]);
                ps2[n] = fmaf(o2 * hv, hv, ps2[n]);
                pza[n] = fmaf(a, o2, pza[n]);
                pah[n] = fmaf(a, hv, pah[n]);
            }
        }
    }
#pragma unroll
    for (int n = 0; n < 4; ++n) {
        pm[n] += __shfl_xor(pm[n], 16); pm[n] += __shfl_xor(pm[n], 32);
        ps2[n] += __shfl_xor(ps2[n], 16); ps2[n] += __shfl_xor(ps2[n], 32);
        pza[n] += __shfl_xor(pza[n], 16); pza[n] += __shfl_xor(pza[n], 32);
        pah[n] += __shfl_xor(pah[n], 16); pah[n] += __shfl_xor(pah[n], 32);
        if (kg == 0) {
            int col = colb + n * 16;
            atomicAdd(&mup[b * ND + col], pm[n]);
            atomicAdd(&s2p[b * ND + col], ps2[n]);
            atomicAdd(&zab[b * ND + col], pza[n]);
            atomicAdd(&ahb[b * ND + col], pah[n]);
        }
    }
}

// ---------------- base GEMM: 1-term Ah*Bh, BK=64 single-buffered, bf16 out ----------------
__global__ __launch_bounds__(256, 4) void k_gemm_base(
    const unsigned short* __restrict__ ht, const unsigned short* __restrict__ bt_h,
    const float* __restrict__ biasb, unsigned short* __restrict__ Out16) {
    constexpr int KC2 = ND / 64;  // 24
    __shared__ __align__(16) unsigned short As[8192];
    __shared__ __align__(16) unsigned short Bh_s[8192];
    int flat = blockIdx.x + 12 * (blockIdx.y + 8 * blockIdx.z);
    int swzf = (flat & 7) * 96 + (flat >> 3);
    int tr = swzf % 12, nt = (swzf / 12) % 8, b = swzf / 96;
    int tid = threadIdx.x;
    int lane = tid & 63, w = tid >> 6;
    int wr = w >> 1, wc = w & 1;
    int l15 = lane & 15, kg = lane >> 4;
    int sw = (l15 >> 1) & 3;
    f32x4 acc[4][4];
#pragma unroll
    for (int m = 0; m < 4; ++m)
#pragma unroll
        for (int n = 0; n < 4; ++n) acc[m][n] = (f32x4){0.f, 0.f, 0.f, 0.f};
    int aoff[4], boff[4];
#pragma unroll
    for (int m = 0; m < 4; ++m) aoff[m] = (wr * 64 + m * 16 + l15) * 32 + ((kg ^ sw) << 3);
#pragma unroll
    for (int n = 0; n < 4; ++n) boff[n] = (wc * 64 + n * 16 + l15) * 32 + ((kg ^ sw) << 3);

    const unsigned short* ga = ht + ((size_t)(b * 12 + tr) * 48) * 4096 + lane * 8;
    const unsigned short* gbh = bt_h + ((size_t)nt * 48) * 4096 + lane * 8;

    for (int kc2 = 0; kc2 < KC2; ++kc2) {
        // 32 segments: As(16) Bh(16); 8 per wave
#pragma unroll
        for (int c = 0; c < 8; ++c) {
            int seg = w * 8 + c;         // 0..31
            int part = seg & 15, mat = seg >> 4;
            const unsigned short* src =
                (mat == 0 ? ga : gbh) + (size_t)kc2 * 8192 + part * 512;
            unsigned short* dst = (mat == 0 ? &As[0] : &Bh_s[0]) + part * 512;
            __builtin_amdgcn_global_load_lds(src, dst, 16, 0, 0);
        }
        __syncthreads();
#pragma unroll
        for (int half = 0; half < 2; ++half) {
            int ho = half * 4096;
            bf16x8 af[4], bh[4];
#pragma unroll
            for (int m = 0; m < 4; ++m) af[m] = *(const bf16x8*)&As[ho + aoff[m]];
#pragma unroll
            for (int n = 0; n < 4; ++n) bh[n] = *(const bf16x8*)&Bh_s[ho + boff[n]];
#pragma unroll
            for (int n = 0; n < 4; ++n)
#pragma unroll
                for (int m = 0; m < 4; ++m)
                    acc[m][n] = __builtin_amdgcn_mfma_f32_16x16x32_bf16(af[m], bh[n], acc[m][n], 0, 0, 0);
        }
        __syncthreads();
    }

    int rowb = tr * 128 + wr * 64 + (kg << 2);
    int colb = nt * 128 + wc * 64 + l15;
#pragma unroll
    for (int m = 0; m < 4; ++m)
#pragma unroll
        for (int q = 0; q < 4; ++q) {
            int row = rowb + m * 16 + q;
            if (row < NT) {
                unsigned short* orow = Out16 + ((size_t)b * NT + row) * NP;
#pragma unroll
                for (int n = 0; n < 4; ++n)
                    orow[colb + n * 16] =
                        bf_rne(acc[m][n][q] + biasb[b * NP + colb + n * 16]);
            }
        }
}

// ---------------- per-iteration small kernels ----------------
// grid (4, 32), block 256
__global__ void k_cvec(const float* __restrict__ C, const float* __restrict__ Wc,
                       float* __restrict__ cvec) {
    int p = blockIdx.x * 256 + threadIdx.x;
    int d0 = blockIdx.y * 48, d1 = d0 + 48;
    float acc[NB];
#pragma unroll
    for (int b = 0; b < NB; ++b) acc[b] = 0.f;
    for (int d = d0; d < d1; ++d) {
        float wc = Wc[(size_t)d * NP + p];
#pragma unroll
        for (int b = 0; b < NB; ++b) acc[b] += C[b * ND + d] * wc;
    }
#pragma unroll
    for (int b = 0; b < NB; ++b) atomicAdd(&cvec[b * NP + p], acc[b]);
}

__global__ void k_softmax(const float* __restrict__ att, const float* __restrict__ energy,
                          const float* __restrict__ b2m, float* __restrict__ A) {
    __shared__ float red[256];
    int b = blockIdx.x, tid = threadIdx.x;
    float bm = b2m[0];
    const float* x = att + (size_t)b * NT;
    const float* en = energy + (size_t)b * NT;
    float* a = A + (size_t)b * NT;
    float mx = -3.4e38f;
    for (int t = tid; t < NT; t += 256) {
        float v = (en[t] * (1.f / ND) > 1e-4f) ? x[t] + bm : NEGINF;
        mx = fmaxf(mx, v);
    }
    red[tid] = mx; __syncthreads();
    for (int s = 128; s > 0; s >>= 1) {
        if (tid < s) red[tid] = fmaxf(red[tid], red[tid + s]);
        __syncthreads();
    }
    mx = red[0]; __syncthreads();
    float sm = 0.f;
    for (int t = tid; t < NT; t += 256) {
        float v = (en[t] * (1.f / ND) > 1e-4f) ? x[t] + bm : NEGINF;
        float e = expf(v - mx); a[t] = e; sm += e;
    }
    float s1 = block_reduce_sum(sm, red);
    float inv1 = 1.f / s1;
    float sm2 = 0.f;
    for (int t = tid; t < NT; t += 256) { float v = a[t] * inv1; a[t] = v; sm2 += v; }
    float s2 = block_reduce_sum(sm2, red);
    float inv2 = 1.f / (s2 + 1e-8f);
    for (int t = tid; t < NT; t += 256) a[t] *= inv2;
}

// parallel emb accumulation: grid 32, block 192
__global__ void k_embacc(const float* __restrict__ red4, const float* __restrict__ w0,
                         float* __restrict__ embt) {
    __shared__ float mus[NB][48], sgs[NB][48];
    int e = threadIdx.x;
    int d0 = blockIdx.x * 48;
    const float* mup = red4;
    const float* s2p = red4 + (size_t)NB * ND;
    for (int idx = e; idx < NB * 48; idx += 192) {
        int b = idx / 48, dd = idx % 48;
        float mu = mup[b * ND + d0 + dd];
        mus[b][dd] = mu;
        sgs[b][dd] = sqrtf(fmaxf(s2p[b * ND + d0 + dd] - mu * mu, 1e-8f));
    }
    __syncthreads();
    float acc[NB];
#pragma unroll
    for (int b = 0; b < NB; ++b) acc[b] = 0.f;
    for (int dd = 0; dd < 48; ++dd) {
        float wa = w0[(size_t)(d0 + dd) * NE + e];
        float wb = w0[(size_t)(ND + d0 + dd) * NE + e];
#pragma unroll
        for (int b = 0; b < NB; ++b)
            acc[b] += mus[b][dd] * wa + sgs[b][dd] * wb;
    }
#pragma unroll
    for (int b = 0; b < NB; ++b) atomicAdd(&embt[b * NE + e], acc[b]);
}

// C-update + stop prob + masked emb-norm write; grid NB, block 256
__global__ void k_tail2(const float* __restrict__ red4, const float* __restrict__ embt,
                        const float* __restrict__ b0, const float* __restrict__ Wstop,
                        const float* __restrict__ bstop, const float* __restrict__ thr,
                        float* __restrict__ Cb, float* __restrict__ stopf,
                        float* __restrict__ Eout, float* __restrict__ Pout, int iter) {
    __shared__ float red[256];
    __shared__ float liveflag;
    int b = blockIdx.x, tid = threadIdx.x;
    const float* Ahb = red4 + (size_t)2 * NB * ND + b * ND;
    const float* zAb = red4 + (size_t)3 * NB * ND + b * ND;
    float active = (stopf[b] > 0.5f) ? 0.f : 1.f;
    float dsum = 0.f;
    for (int d = tid; d < ND; d += 256) {
        float Cn = Cb[b * ND + d] + active * (Ahb[d] * (1.f / NT));
        Cb[b * ND + d] = Cn;
        dsum += zAb[d] * Wstop[d] + Cn * Wstop[ND + d];
    }
    float s = block_reduce_sum(dsum, red);
    if (tid == 0) {
        float logit = s + bstop[0];
        float p = 1.f / (1.f + expf(-logit));
        Pout[b * NITER + iter] = p;
        bool newly = p < thr[0];
        if (newly) stopf[b] = 1.f;
        liveflag = (active > 0.5f && !newly) ? 1.f : 0.f;
    }
    __syncthreads();
    float live = liveflag;
    float emb = (tid < NE) ? (embt[b * NE + tid] + b0[tid]) : 0.f;
    float nrm = block_reduce_sum(emb * emb, red);
    float sc = live / fmaxf(sqrtf(nrm), 1e-12f);
    if (tid < NE) Eout[((size_t)b * NITER + iter) * NE + tid] = emb * sc;
}

// ---------------- launch ----------------
extern "C" void kernel_launch(void* const* d_in, const int* in_sizes, int n_in,
                              void* d_out, int out_size, void* d_ws, size_t ws_size,
                              hipStream_t stream) {
    const float* h = (const float*)d_in[0];
    const float* W1 = (const float*)d_in[1];
    const float* Wc = (const float*)d_in[2];
    const float* W2 = (const float*)d_in[3];
    const float* b2 = (const float*)d_in[4];
    const float* w0 = (const float*)d_in[5];
    const float* b0 = (const float*)d_in[6];
    const float* Wstop = (const float*)d_in[7];
    const float* bstop = (const float*)d_in[8];
    const float* thr = (const float*)d_in[9];
    const float* C0 = (const float*)d_in[10];

    float* Eout = (float*)d_out;
    float* Pout = Eout + (size_t)NB * NITER * NE;

    char* wsb = (char*)d_ws;
    size_t off = 0;
    auto alloc = [&](size_t bytes) -> void* {
        void* p = wsb + off; off += (bytes + 15) & ~(size_t)15; return p;
    };

    unsigned short* base16 = (unsigned short*)alloc((size_t)NB * NT * NP * 2);
    unsigned short* rel_h = (unsigned short*)alloc((size_t)NB * 12 * 32 * 4096 * 2);
    unsigned short* ht_h = (unsigned short*)alloc((size_t)NB * 12 * 48 * 4096 * 2);
    unsigned short* w1t_h = (unsigned short*)alloc((size_t)8 * 48 * 4096 * 2);
    unsigned short* w1t_l = (unsigned short*)alloc((size_t)8 * 48 * 4096 * 2);
    unsigned short* w2t_h = (unsigned short*)alloc((size_t)12 * 32 * 4096 * 2);
    unsigned short* w2t_l = (unsigned short*)alloc((size_t)12 * 32 * 4096 * 2);
    // pre-pass zero region: mu0 | sig0 | energy | biasb (one memset)
    size_t pz = (size_t)2 * NB * ND + NB * NT + NB * NP;
    float* mu0 = (float*)alloc(pz * 4);
    float* sig0 = mu0 + NB * ND;
    float* energy = sig0 + NB * ND;
    float* biasb = energy + NB * NT;
    float* w2r = (float*)alloc(NP * 4);
    float* b2m = (float*)alloc(16);
    // per-iter zero region: cvec | att | red4 | embt
    size_t zelems = (size_t)NB * NP + NB * NT + 4 * NB * ND + NB * NE;
    float* cvec = (float*)alloc(zelems * 4);
    float* att = cvec + NB * NP;
    float* red4 = att + NB * NT;
    float* mup = red4;
    float* s2p = red4 + NB * ND;
    float* Ahb = red4 + 2 * NB * ND;
    float* zAb = red4 + 3 * NB * ND;
    float* embt = red4 + 4 * NB * ND;
    float* Abuf = (float*)alloc(NB * NT * 4);
    float* Cb = (float*)alloc(NB * ND * 4);
    float* stopf = (float*)alloc(32);
    size_t zero_bytes = zelems * 4;

    // ---- pre-pass ----
    hipMemsetAsync(mu0, 0, pz * 4, stream);
    k_colstats<<<dim3(ND / 256, NB, 12), 256, 0, stream>>>(h, mu0, sig0);
    k_stats_fin<<<dim3(NB * ND / 256), 256, 0, stream>>>(mu0, sig0);
    k_w2r<<<dim3(NP + 1), 256, 0, stream>>>(W2, b2, w2r, b2m);
    k_biasb<<<dim3(4, 96), 256, 0, stream>>>(W1, mu0, sig0, biasb);
    k_split_w<<<dim3(8, 48), 256, 0, stream>>>(W1, NP, 48, w1t_h, w1t_l);
    k_split_w<<<dim3(12, 32), 256, 0, stream>>>(W2, ND, 32, w2t_h, w2t_l);
    k_split_h<<<dim3(12, 48, NB), 256, 0, stream>>>(h, ht_h, energy);
    k_gemm_base<<<dim3(12, 8, NB), 256, 0, stream>>>(ht_h, w1t_h, biasb, base16);
    k_init<<<dim3(ND / 256, NB), 256, 0, stream>>>(Cb, C0, stopf);

    // ---- iterations ----
    for (int i = 0; i < NITER; ++i) {
        hipMemsetAsync(cvec, 0, zero_bytes, stream);
        k_cvec<<<dim3(4, 32), 256, 0, stream>>>(Cb, Wc, cvec);
        k_relu_att<<<dim3(12, 32, NB), 256, 0, stream>>>(base16, cvec, w2r, rel_h, att);
        k_softmax<<<dim3(NB), 256, 0, stream>>>(att, energy, b2m, Abuf);
        k_gemm_relu<<<dim3(12, 12, NB), 256, 0, stream>>>(
            ht_h, rel_h, w2t_h, b2, Abuf, mup, s2p, zAb, Ahb);
        k_embacc<<<dim3(32), 192, 0, stream>>>(red4, w0, embt);
        k_tail2<<<dim3(NB), 256, 0, stream>>>(red4, embt, b0, Wstop, bstop, thr,
                                              Cb, stopf, Eout, Pout, i);
    }
}

// Round 13
// 916.723 us; speedup vs baseline: 1.3052x; 1.1405x over previous
//
#include <hip/hip_runtime.h>
#include <math.h>

#define NB 8
#define NT 1500
#define ND 1536
#define NP 1024
#define NE 192
#define NITER 6
#define NEGINF -1e30f

typedef __attribute__((ext_vector_type(8))) short bf16x8;
typedef __attribute__((ext_vector_type(4))) float f32x4;
typedef __attribute__((ext_vector_type(8))) unsigned short us16x8;

__device__ __forceinline__ unsigned short bf_rne(float x) {
    unsigned u = __float_as_uint(x);
    return (unsigned short)((u + 0x7FFFu + ((u >> 16) & 1u)) >> 16);
}
__device__ __forceinline__ float bf_f(unsigned short u) {
    return __uint_as_float(((unsigned)u) << 16);
}

// ---------------- helpers ----------------
__device__ __forceinline__ float block_reduce_sum(float v, float* red) {
    int tid = threadIdx.x;
    red[tid] = v; __syncthreads();
    for (int s = blockDim.x >> 1; s > 0; s >>= 1) {
        if (tid < s) red[tid] += red[tid + s];
        __syncthreads();
    }
    float r = red[0]; __syncthreads();
    return r;
}

// ---------------- pre-pass kernels ----------------
__global__ void k_colstats(const float* __restrict__ h, float* __restrict__ sum1,
                           float* __restrict__ sum2) {
    int d = blockIdx.x * 256 + threadIdx.x;
    int b = blockIdx.y;
    int t0 = blockIdx.z * 125, t1 = t0 + 125;
    const float* hp = h + (size_t)b * NT * ND + d;
    float s = 0.f, s2 = 0.f;
    for (int t = t0; t < t1; ++t) { float v = hp[(size_t)t * ND]; s += v; s2 += v * v; }
    atomicAdd(&sum1[b * ND + d], s);
    atomicAdd(&sum2[b * ND + d], s2);
}

__global__ void k_stats_fin(float* __restrict__ mu0, float* __restrict__ sig0) {
    int i = blockIdx.x * 256 + threadIdx.x;
    float mu = mu0[i] * (1.f / NT);
    float sec = sig0[i] * (1.f / NT);
    mu0[i] = mu;
    sig0[i] = sqrtf(fmaxf(sec - mu * mu, 1e-8f));
}

__global__ void k_w2r(const float* __restrict__ W2, const float* __restrict__ b2,
                      float* __restrict__ w2r, float* __restrict__ b2m) {
    __shared__ float red[256];
    int p = blockIdx.x;
    float s = 0.f;
    if (p < NP) {
        const float* row = W2 + (size_t)p * ND;
        for (int d = threadIdx.x; d < ND; d += 256) s += row[d];
        s = block_reduce_sum(s, red);
        if (threadIdx.x == 0) w2r[p] = s * (1.f / ND);
    } else {
        for (int d = threadIdx.x; d < ND; d += 256) s += b2[d];
        s = block_reduce_sum(s, red);
        if (threadIdx.x == 0) b2m[0] = s * (1.f / ND);
    }
}

// grid (4, 96), block 256
__global__ void k_biasb(const float* __restrict__ W1, const float* __restrict__ mu0,
                        const float* __restrict__ sig0, float* __restrict__ biasb) {
    int p = blockIdx.x * 256 + threadIdx.x;
    int d0 = blockIdx.y * 16, d1 = d0 + 16;
    float acc[NB];
#pragma unroll
    for (int b = 0; b < NB; ++b) acc[b] = 0.f;
    for (int d = d0; d < d1; ++d) {
        float wa = W1[(size_t)(ND + d) * NP + p];
        float wb = W1[(size_t)(2 * ND + d) * NP + p];
#pragma unroll
        for (int b = 0; b < NB; ++b)
            acc[b] += mu0[b * ND + d] * wa + sig0[b * ND + d] * wb;
    }
#pragma unroll
    for (int b = 0; b < NB; ++b) atomicAdd(&biasb[b * NP + p], acc[b]);
}

__global__ void k_init(float* __restrict__ C, const float* __restrict__ C0,
                       float* __restrict__ stopf) {
    int d = blockIdx.x * 256 + threadIdx.x;
    int b = blockIdx.y;
    C[b * ND + d] = C0[d];
    if (blockIdx.x == 0 && threadIdx.x == 0) stopf[b] = 0.f;
}

// ---------------- weight split (once): W [K][N] f32 -> tiled swizzled bf16 hi/lo ----------------
__global__ void k_split_w(const float* __restrict__ W, int ldw, int kcnt,
                          unsigned short* __restrict__ th, unsigned short* __restrict__ tl) {
    __shared__ float t[128][33];
    int nt = blockIdx.x, kc = blockIdx.y, tid = threadIdx.x;
    int col = tid & 127, kh = tid >> 7;
    const float* wp = W + (size_t)(kc * 32 + kh) * ldw + nt * 128 + col;
#pragma unroll
    for (int i = 0; i < 16; ++i)
        t[col][kh + 2 * i] = wp[(size_t)(2 * i) * ldw];
    __syncthreads();
    int r = tid >> 1;
    int swz = (r >> 1) & 3;
    size_t tb = ((size_t)nt * kcnt + kc) * 4096;
#pragma unroll
    for (int j = 0; j < 2; ++j) {
        int so = (tid & 1) * 2 + j;
        int s = so ^ swz;
        us16x8 hv, lv;
#pragma unroll
        for (int q = 0; q < 8; ++q) {
            float x = t[r][s * 8 + q];
            unsigned short hh = bf_rne(x);
            hv[q] = hh;
            lv[q] = bf_rne(x - bf_f(hh));
        }
        *(us16x8*)&th[tb + r * 32 + so * 8] = hv;
        *(us16x8*)&tl[tb + r * 32 + so * 8] = lv;
    }
}

// ---------------- h split (once): h f32 -> tiled swizzled bf16 hi + energy row sums ----------------
// grid (12, 48, NB), block 256
__global__ void k_split_h(const float* __restrict__ h, unsigned short* __restrict__ th,
                          float* __restrict__ energy) {
    int tr = blockIdx.x, kc = blockIdx.y, b = blockIdx.z;
    int tid = threadIdx.x;
    int r = tid >> 1, quad = tid & 1;
    int row = tr * 128 + r;
    bool ok = row < NT;
    size_t tb = ((size_t)(b * 12 + tr) * 48 + kc) * 4096;
    const float* hp = h + ((size_t)b * NT + (ok ? row : 0)) * ND + kc * 32 + quad * 16;
    int swz = (r >> 1) & 3;
    float es = 0.f;
#pragma unroll
    for (int half = 0; half < 2; ++half) {
        us16x8 hv;
#pragma unroll
        for (int j = 0; j < 2; ++j) {
            float x0 = 0.f, x1 = 0.f, x2 = 0.f, x3 = 0.f;
            if (ok) {
                float4 v = *(const float4*)(hp + half * 8 + j * 4);
                x0 = v.x; x1 = v.y; x2 = v.z; x3 = v.w;
                es += x0 * x0 + x1 * x1 + x2 * x2 + x3 * x3;
            }
            hv[j * 4 + 0] = bf_rne(x0); hv[j * 4 + 1] = bf_rne(x1);
            hv[j * 4 + 2] = bf_rne(x2); hv[j * 4 + 3] = bf_rne(x3);
        }
        int off = r * 32 + (((quad * 2 + half) ^ swz) << 3);
        *(us16x8*)&th[tb + off] = hv;
    }
    es += __shfl_xor(es, 1);
    if (ok && quad == 0) atomicAdd(&energy[b * NT + row], es);
}

// ---------------- per-iter fused: relu(bf16 base + cvec) -> hi tile, + att partial sums ----------------
// grid (12, 32, NB), block 256
__global__ void k_relu_att(const unsigned short* __restrict__ base16,
                           const float* __restrict__ cvec, const float* __restrict__ w2r,
                           unsigned short* __restrict__ th, float* __restrict__ att) {
    int tr = blockIdx.x, kc = blockIdx.y, b = blockIdx.z;
    int tid = threadIdx.x;
    int r = tid >> 1, quad = tid & 1;
    int row = tr * 128 + r;
    bool ok = row < NT;
    size_t tb = ((size_t)(b * 12 + tr) * 32 + kc) * 4096;
    const unsigned short* bp = base16 + ((size_t)b * NT + (ok ? row : 0)) * NP + kc * 32 + quad * 16;
    const float* cv = cvec + b * NP + kc * 32 + quad * 16;
    const float* wr = w2r + kc * 32 + quad * 16;
    int swz = (r >> 1) & 3;
    float asum = 0.f;
#pragma unroll
    for (int half = 0; half < 2; ++half) {
        us16x8 bv = (us16x8){0, 0, 0, 0, 0, 0, 0, 0};
        if (ok) bv = *(const us16x8*)(bp + half * 8);
        us16x8 hv;
#pragma unroll
        for (int j = 0; j < 2; ++j) {
            float4 c4 = *(const float4*)(cv + half * 8 + j * 4);
            float4 w4 = *(const float4*)(wr + half * 8 + j * 4);
            float x0 = fmaxf(bf_f(bv[j * 4 + 0]) + c4.x, 0.f);
            float x1 = fmaxf(bf_f(bv[j * 4 + 1]) + c4.y, 0.f);
            float x2 = fmaxf(bf_f(bv[j * 4 + 2]) + c4.z, 0.f);
            float x3 = fmaxf(bf_f(bv[j * 4 + 3]) + c4.w, 0.f);
            if (ok) asum += x0 * w4.x + x1 * w4.y + x2 * w4.z + x3 * w4.w;
            hv[j * 4 + 0] = bf_rne(x0); hv[j * 4 + 1] = bf_rne(x1);
            hv[j * 4 + 2] = bf_rne(x2); hv[j * 4 + 3] = bf_rne(x3);
        }
        int off = r * 32 + (((quad * 2 + half) ^ swz) << 3);
        *(us16x8*)&th[tb + off] = hv;
    }
    asum += __shfl_xor(asum, 1);
    if (ok && quad == 0) atomicAdd(&att[b * NT + row], asum);
}

// ---------------- RELU GEMM: 1-term bf16, dbuf BK=32; epilogue h via LDS restage ----------------
__global__ __launch_bounds__(256, 4) void k_gemm_relu(
    const unsigned short* __restrict__ ht, const unsigned short* __restrict__ at_h,
    const unsigned short* __restrict__ bt_h, const float* __restrict__ b2,
    const float* __restrict__ Aw, float* __restrict__ mup, float* __restrict__ s2p,
    float* __restrict__ zab, float* __restrict__ ahb) {
    constexpr int KC = NP / 32;  // 32
    __shared__ __align__(16) unsigned short SM[16384];  // As[2][4096] | Bs[2][4096]; reused as h tile
    int flat = blockIdx.x + 12 * (blockIdx.y + 12 * blockIdx.z);
    int swzf = (flat & 7) * 144 + (flat >> 3);
    int tr = swzf % 12, nt = (swzf / 12) % 12, b = swzf / 144;
    int tid = threadIdx.x;
    int lane = tid & 63, w = tid >> 6;
    int wr = w >> 1, wc = w & 1;
    int l15 = lane & 15, kg = lane >> 4;
    int sw = (l15 >> 1) & 3;
    f32x4 acc[4][4];
#pragma unroll
    for (int m = 0; m < 4; ++m)
#pragma unroll
        for (int n = 0; n < 4; ++n) acc[m][n] = (f32x4){0.f, 0.f, 0.f, 0.f};
    int aoff[4], boff[4];
#pragma unroll
    for (int m = 0; m < 4; ++m) aoff[m] = (wr * 64 + m * 16 + l15) * 32 + ((kg ^ sw) << 3);
#pragma unroll
    for (int n = 0; n < 4; ++n) boff[n] = (wc * 64 + n * 16 + l15) * 32 + ((kg ^ sw) << 3);

    const unsigned short* ga = at_h + ((size_t)(b * 12 + tr) * KC) * 4096 + lane * 8;
    const unsigned short* gb = bt_h + ((size_t)nt * KC) * 4096 + lane * 8;

    auto stage = [&](int buf, int kc) {
#pragma unroll
        for (int c = 0; c < 4; ++c) {
            int seg = w * 4 + c;
            int part_ = seg & 7;
            const unsigned short* src = ((seg >> 3) == 0 ? ga : gb) + (size_t)kc * 4096 + part_ * 512;
            unsigned short* dst = ((seg >> 3) == 0 ? &SM[buf * 4096] : &SM[8192 + buf * 4096]) + part_ * 512;
            __builtin_amdgcn_global_load_lds(src, dst, 16, 0, 0);
        }
    };

    stage(0, 0);
    __syncthreads();
    int cur = 0;
    for (int kc = 0; kc < KC; ++kc) {
        if (kc + 1 < KC) stage(cur ^ 1, kc + 1);
        bf16x8 af[4], bfr[4];
#pragma unroll
        for (int m = 0; m < 4; ++m) af[m] = *(const bf16x8*)&SM[cur * 4096 + aoff[m]];
#pragma unroll
        for (int n = 0; n < 4; ++n) bfr[n] = *(const bf16x8*)&SM[8192 + cur * 4096 + boff[n]];
#pragma unroll
        for (int n = 0; n < 4; ++n)
#pragma unroll
            for (int m = 0; m < 4; ++m)
                acc[m][n] = __builtin_amdgcn_mfma_f32_16x16x32_bf16(af[m], bfr[n], acc[m][n], 0, 0, 0);
        __syncthreads();
        cur ^= 1;
    }

    // ---- restage this block's 128x128 h subtile into LDS (coalesced), XOR bank-swizzled ----
    const unsigned short* htb = ht + (size_t)(b * 12 + tr) * 48 * 4096;
#pragma unroll
    for (int c8 = 0; c8 < 8; ++c8) {
        int chunk = tid + 256 * c8;           // 0..2047
        int so = chunk & 3, r = (chunk >> 2) & 127, g = chunk >> 9;  // g: 0..3
        us16x8 v = *(const us16x8*)&htb[(size_t)(nt * 4 + g) * 4096 + r * 32 + so * 8];
        int s = so ^ ((r >> 1) & 3);          // undo tile swizzle -> col group within 32
        int st = (g * 4 + s) ^ ((r >> 2) & 7);  // bank swizzle
        *(us16x8*)&SM[r * 128 + st * 8] = v;
    }
    __syncthreads();

    int rowb = tr * 128 + wr * 64 + (kg << 2);
    int colb = nt * 128 + wc * 64 + l15;
    float b2c[4];
#pragma unroll
    for (int n = 0; n < 4; ++n) b2c[n] = b2[colb + n * 16];
    float pm[4] = {0, 0, 0, 0}, ps2[4] = {0, 0, 0, 0}, pza[4] = {0, 0, 0, 0}, pah[4] = {0, 0, 0, 0};
#pragma unroll
    for (int m = 0; m < 4; ++m) {
#pragma unroll
        for (int q = 0; q < 4; ++q) {
            int row = rowb + m * 16 + q;
            int r_in = wr * 64 + (kg << 2) + m * 16 + q;
            bool ok = row < NT;
            float okf = ok ? 1.f : 0.f;
            float a = Aw[b * NT + (ok ? row : (NT - 1))] * okf;
            int rx = (r_in >> 2) & 7;
#pragma unroll
            for (int n = 0; n < 4; ++n) {
                int cl = wc * 64 + n * 16 + l15;
                float hv = bf_f(SM[r_in * 128 + ((((cl >> 3) ^ rx) << 3) | (cl & 7))]) * okf;
                float o2 = acc[m][n][q] + b2c[n];
                pm[n] = fmaf(o2, hv, pm[n]);
                ps2[n] = fmaf(o2 * hv, hv, ps2[n]);
                pza[n] = fmaf(a, o2, pza[n]);
                pah[n] = fmaf(a, hv, pah[n]);
            }
        }
    }
#pragma unroll
    for (int n = 0; n < 4; ++n) {
        pm[n] += __shfl_xor(pm[n], 16); pm[n] += __shfl_xor(pm[n], 32);
        ps2[n] += __shfl_xor(ps2[n], 16); ps2[n] += __shfl_xor(ps2[n], 32);
        pza[n] += __shfl_xor(pza[n], 16); pza[n] += __shfl_xor(pza[n], 32);
        pah[n] += __shfl_xor(pah[n], 16); pah[n] += __shfl_xor(pah[n], 32);
        if (kg == 0) {
            int col = colb + n * 16;
            atomicAdd(&mup[b * ND + col], pm[n]);
            atomicAdd(&s2p[b * ND + col], ps2[n]);
            atomicAdd(&zab[b * ND + col], pza[n]);
            atomicAdd(&ahb[b * ND + col], pah[n]);
        }
    }
}

// ---------------- base GEMM: 1-term Ah*Bh, BK=64 single-buffered, bf16 out ----------------
__global__ __launch_bounds__(256, 4) void k_gemm_base(
    const unsigned short* __restrict__ ht, const unsigned short* __restrict__ bt_h,
    const float* __restrict__ biasb, unsigned short* __restrict__ Out16) {
    constexpr int KC2 = ND / 64;  // 24
    __shared__ __align__(16) unsigned short As[8192];
    __shared__ __align__(16) unsigned short Bh_s[8192];
    int flat = blockIdx.x + 12 * (blockIdx.y + 8 * blockIdx.z);
    int swzf = (flat & 7) * 96 + (flat >> 3);
    int tr = swzf % 12, nt = (swzf / 12) % 8, b = swzf / 96;
    int tid = threadIdx.x;
    int lane = tid & 63, w = tid >> 6;
    int wr = w >> 1, wc = w & 1;
    int l15 = lane & 15, kg = lane >> 4;
    int sw = (l15 >> 1) & 3;
    f32x4 acc[4][4];
#pragma unroll
    for (int m = 0; m < 4; ++m)
#pragma unroll
        for (int n = 0; n < 4; ++n) acc[m][n] = (f32x4){0.f, 0.f, 0.f, 0.f};
    int aoff[4], boff[4];
#pragma unroll
    for (int m = 0; m < 4; ++m) aoff[m] = (wr * 64 + m * 16 + l15) * 32 + ((kg ^ sw) << 3);
#pragma unroll
    for (int n = 0; n < 4; ++n) boff[n] = (wc * 64 + n * 16 + l15) * 32 + ((kg ^ sw) << 3);

    const unsigned short* ga = ht + ((size_t)(b * 12 + tr) * 48) * 4096 + lane * 8;
    const unsigned short* gbh = bt_h + ((size_t)nt * 48) * 4096 + lane * 8;

    for (int kc2 = 0; kc2 < KC2; ++kc2) {
        // 32 segments: As(16) Bh(16); 8 per wave
#pragma unroll
        for (int c = 0; c < 8; ++c) {
            int seg = w * 8 + c;         // 0..31
            int part = seg & 15, mat = seg >> 4;
            const unsigned short* src =
                (mat == 0 ? ga : gbh) + (size_t)kc2 * 8192 + part * 512;
            unsigned short* dst = (mat == 0 ? &As[0] : &Bh_s[0]) + part * 512;
            __builtin_amdgcn_global_load_lds(src, dst, 16, 0, 0);
        }
        __syncthreads();
#pragma unroll
        for (int half = 0; half < 2; ++half) {
            int ho = half * 4096;
            bf16x8 af[4], bh[4];
#pragma unroll
            for (int m = 0; m < 4; ++m) af[m] = *(const bf16x8*)&As[ho + aoff[m]];
#pragma unroll
            for (int n = 0; n < 4; ++n) bh[n] = *(const bf16x8*)&Bh_s[ho + boff[n]];
#pragma unroll
            for (int n = 0; n < 4; ++n)
#pragma unroll
                for (int m = 0; m < 4; ++m)
                    acc[m][n] = __builtin_amdgcn_mfma_f32_16x16x32_bf16(af[m], bh[n], acc[m][n], 0, 0, 0);
        }
        __syncthreads();
    }

    int rowb = tr * 128 + wr * 64 + (kg << 2);
    int colb = nt * 128 + wc * 64 + l15;
#pragma unroll
    for (int m = 0; m < 4; ++m)
#pragma unroll
        for (int q = 0; q < 4; ++q) {
            int row = rowb + m * 16 + q;
            if (row < NT) {
                unsigned short* orow = Out16 + ((size_t)b * NT + row) * NP;
#pragma unroll
                for (int n = 0; n < 4; ++n)
                    orow[colb + n * 16] =
                        bf_rne(acc[m][n][q] + biasb[b * NP + colb + n * 16]);
            }
        }
}

// ---------------- per-iteration small kernels ----------------
// grid (4, 32), block 256
__global__ void k_cvec(const float* __restrict__ C, const float* __restrict__ Wc,
                       float* __restrict__ cvec) {
    int p = blockIdx.x * 256 + threadIdx.x;
    int d0 = blockIdx.y * 48, d1 = d0 + 48;
    float acc[NB];
#pragma unroll
    for (int b = 0; b < NB; ++b) acc[b] = 0.f;
    for (int d = d0; d < d1; ++d) {
        float wc = Wc[(size_t)d * NP + p];
#pragma unroll
        for (int b = 0; b < NB; ++b) acc[b] += C[b * ND + d] * wc;
    }
#pragma unroll
    for (int b = 0; b < NB; ++b) atomicAdd(&cvec[b * NP + p], acc[b]);
}

__global__ void k_softmax(const float* __restrict__ att, const float* __restrict__ energy,
                          const float* __restrict__ b2m, float* __restrict__ A) {
    __shared__ float red[256];
    int b = blockIdx.x, tid = threadIdx.x;
    float bm = b2m[0];
    const float* x = att + (size_t)b * NT;
    const float* en = energy + (size_t)b * NT;
    float* a = A + (size_t)b * NT;
    float mx = -3.4e38f;
    for (int t = tid; t < NT; t += 256) {
        float v = (en[t] * (1.f / ND) > 1e-4f) ? x[t] + bm : NEGINF;
        mx = fmaxf(mx, v);
    }
    red[tid] = mx; __syncthreads();
    for (int s = 128; s > 0; s >>= 1) {
        if (tid < s) red[tid] = fmaxf(red[tid], red[tid + s]);
        __syncthreads();
    }
    mx = red[0]; __syncthreads();
    float sm = 0.f;
    for (int t = tid; t < NT; t += 256) {
        float v = (en[t] * (1.f / ND) > 1e-4f) ? x[t] + bm : NEGINF;
        float e = expf(v - mx); a[t] = e; sm += e;
    }
    float s1 = block_reduce_sum(sm, red);
    float inv1 = 1.f / s1;
    float sm2 = 0.f;
    for (int t = tid; t < NT; t += 256) { float v = a[t] * inv1; a[t] = v; sm2 += v; }
    float s2 = block_reduce_sum(sm2, red);
    float inv2 = 1.f / (s2 + 1e-8f);
    for (int t = tid; t < NT; t += 256) a[t] *= inv2;
}

// parallel emb accumulation: grid 32, block 192
__global__ void k_embacc(const float* __restrict__ red4, const float* __restrict__ w0,
                         float* __restrict__ embt) {
    __shared__ float mus[NB][48], sgs[NB][48];
    int e = threadIdx.x;
    int d0 = blockIdx.x * 48;
    const float* mup = red4;
    const float* s2p = red4 + (size_t)NB * ND;
    for (int idx = e; idx < NB * 48; idx += 192) {
        int b = idx / 48, dd = idx % 48;
        float mu = mup[b * ND + d0 + dd];
        mus[b][dd] = mu;
        sgs[b][dd] = sqrtf(fmaxf(s2p[b * ND + d0 + dd] - mu * mu, 1e-8f));
    }
    __syncthreads();
    float acc[NB];
#pragma unroll
    for (int b = 0; b < NB; ++b) acc[b] = 0.f;
    for (int dd = 0; dd < 48; ++dd) {
        float wa = w0[(size_t)(d0 + dd) * NE + e];
        float wb = w0[(size_t)(ND + d0 + dd) * NE + e];
#pragma unroll
        for (int b = 0; b < NB; ++b)
            acc[b] += mus[b][dd] * wa + sgs[b][dd] * wb;
    }
#pragma unroll
    for (int b = 0; b < NB; ++b) atomicAdd(&embt[b * NE + e], acc[b]);
}

// C-update + stop prob + masked emb-norm write; grid NB, block 256
__global__ void k_tail2(const float* __restrict__ red4, const float* __restrict__ embt,
                        const float* __restrict__ b0, const float* __restrict__ Wstop,
                        const float* __restrict__ bstop, const float* __restrict__ thr,
                        float* __restrict__ Cb, float* __restrict__ stopf,
                        float* __restrict__ Eout, float* __restrict__ Pout, int iter) {
    __shared__ float red[256];
    __shared__ float liveflag;
    int b = blockIdx.x, tid = threadIdx.x;
    const float* Ahb = red4 + (size_t)2 * NB * ND + b * ND;
    const float* zAb = red4 + (size_t)3 * NB * ND + b * ND;
    float active = (stopf[b] > 0.5f) ? 0.f : 1.f;
    float dsum = 0.f;
    for (int d = tid; d < ND; d += 256) {
        float Cn = Cb[b * ND + d] + active * (Ahb[d] * (1.f / NT));
        Cb[b * ND + d] = Cn;
        dsum += zAb[d] * Wstop[d] + Cn * Wstop[ND + d];
    }
    float s = block_reduce_sum(dsum, red);
    if (tid == 0) {
        float logit = s + bstop[0];
        float p = 1.f / (1.f + expf(-logit));
        Pout[b * NITER + iter] = p;
        bool newly = p < thr[0];
        if (newly) stopf[b] = 1.f;
        liveflag = (active > 0.5f && !newly) ? 1.f : 0.f;
    }
    __syncthreads();
    float live = liveflag;
    float emb = (tid < NE) ? (embt[b * NE + tid] + b0[tid]) : 0.f;
    float nrm = block_reduce_sum(emb * emb, red);
    float sc = live / fmaxf(sqrtf(nrm), 1e-12f);
    if (tid < NE) Eout[((size_t)b * NITER + iter) * NE + tid] = emb * sc;
}

// ---------------- launch ----------------
extern "C" void kernel_launch(void* const* d_in, const int* in_sizes, int n_in,
                              void* d_out, int out_size, void* d_ws, size_t ws_size,
                              hipStream_t stream) {
    const float* h = (const float*)d_in[0];
    const float* W1 = (const float*)d_in[1];
    const float* Wc = (const float*)d_in[2];
    const float* W2 = (const float*)d_in[3];
    const float* b2 = (const float*)d_in[4];
    const float* w0 = (const float*)d_in[5];
    const float* b0 = (const float*)d_in[6];
    const float* Wstop = (const float*)d_in[7];
    const float* bstop = (const float*)d_in[8];
    const float* thr = (const float*)d_in[9];
    const float* C0 = (const float*)d_in[10];

    float* Eout = (float*)d_out;
    float* Pout = Eout + (size_t)NB * NITER * NE;

    char* wsb = (char*)d_ws;
    size_t off = 0;
    auto alloc = [&](size_t bytes) -> void* {
        void* p = wsb + off; off += (bytes + 15) & ~(size_t)15; return p;
    };

    unsigned short* base16 = (unsigned short*)alloc((size_t)NB * NT * NP * 2);
    unsigned short* rel_h = (unsigned short*)alloc((size_t)NB * 12 * 32 * 4096 * 2);
    unsigned short* ht_h = (unsigned short*)alloc((size_t)NB * 12 * 48 * 4096 * 2);
    unsigned short* w1t_h = (unsigned short*)alloc((size_t)8 * 48 * 4096 * 2);
    unsigned short* w1t_l = (unsigned short*)alloc((size_t)8 * 48 * 4096 * 2);
    unsigned short* w2t_h = (unsigned short*)alloc((size_t)12 * 32 * 4096 * 2);
    unsigned short* w2t_l = (unsigned short*)alloc((size_t)12 * 32 * 4096 * 2);
    // pre-pass zero region: mu0 | sig0 | energy | biasb (one memset)
    size_t pz = (size_t)2 * NB * ND + NB * NT + NB * NP;
    float* mu0 = (float*)alloc(pz * 4);
    float* sig0 = mu0 + NB * ND;
    float* energy = sig0 + NB * ND;
    float* biasb = energy + NB * NT;
    float* w2r = (float*)alloc(NP * 4);
    float* b2m = (float*)alloc(16);
    // per-iter zero region: cvec | att | red4 | embt
    size_t zelems = (size_t)NB * NP + NB * NT + 4 * NB * ND + NB * NE;
    float* cvec = (float*)alloc(zelems * 4);
    float* att = cvec + NB * NP;
    float* red4 = att + NB * NT;
    float* mup = red4;
    float* s2p = red4 + NB * ND;
    float* Ahb = red4 + 2 * NB * ND;
    float* zAb = red4 + 3 * NB * ND;
    float* embt = red4 + 4 * NB * ND;
    float* Abuf = (float*)alloc(NB * NT * 4);
    float* Cb = (float*)alloc(NB * ND * 4);
    float* stopf = (float*)alloc(32);
    size_t zero_bytes = zelems * 4;

    // ---- pre-pass ----
    hipMemsetAsync(mu0, 0, pz * 4, stream);
    k_colstats<<<dim3(ND / 256, NB, 12), 256, 0, stream>>>(h, mu0, sig0);
    k_stats_fin<<<dim3(NB * ND / 256), 256, 0, stream>>>(mu0, sig0);
    k_w2r<<<dim3(NP + 1), 256, 0, stream>>>(W2, b2, w2r, b2m);
    k_biasb<<<dim3(4, 96), 256, 0, stream>>>(W1, mu0, sig0, biasb);
    k_split_w<<<dim3(8, 48), 256, 0, stream>>>(W1, NP, 48, w1t_h, w1t_l);
    k_split_w<<<dim3(12, 32), 256, 0, stream>>>(W2, ND, 32, w2t_h, w2t_l);
    k_split_h<<<dim3(12, 48, NB), 256, 0, stream>>>(h, ht_h, energy);
    k_gemm_base<<<dim3(12, 8, NB), 256, 0, stream>>>(ht_h, w1t_h, biasb, base16);
    k_init<<<dim3(ND / 256, NB), 256, 0, stream>>>(Cb, C0, stopf);

    // ---- iterations ----
    for (int i = 0; i < NITER; ++i) {
        hipMemsetAsync(cvec, 0, zero_bytes, stream);
        k_cvec<<<dim3(4, 32), 256, 0, stream>>>(Cb, Wc, cvec);
        k_relu_att<<<dim3(12, 32, NB), 256, 0, stream>>>(base16, cvec, w2r, rel_h, att);
        k_softmax<<<dim3(NB), 256, 0, stream>>>(att, energy, b2m, Abuf);
        k_gemm_relu<<<dim3(12, 12, NB), 256, 0, stream>>>(
            ht_h, rel_h, w2t_h, b2, Abuf, mup, s2p, zAb, Ahb);
        k_embacc<<<dim3(32), 192, 0, stream>>>(red4, w0, embt);
        k_tail2<<<dim3(NB), 256, 0, stream>>>(red4, embt, b0, Wstop, bstop, thr,
                                              Cb, stopf, Eout, Pout, i);
    }
}